// Round 15
// baseline (45.842 us; speedup 1.0000x reference)
//
#include <hip/hip_runtime.h>
#include <hip/hip_bf16.h>

// LogicConv3d: B=64, C=32, H=32, W=32, K=64, P=784, S=16 gathers/side.
// R15: R10 dual-pipe + p-half LDS split for 2x occupancy.
//  - All pipes model at <=9us yet kernel ~29us -> latency-bound at 4
//    waves/SIMD (1 block/CU, forced by the 128KB image tile).
//  - p-rows [0,14) only touch image rows [0,18); rows [14,28) touch [14,32).
//    Stage 18 rows x 32ch = 72KB per block -> 2 blocks/CU = 8 waves/SIMD.
//  - LDS base folds ph away: baseL=(c*576+h_off*32+w_off)*4, disp=8t+16(t/14)
//    (t local in [0,196)); odd-image global ptr absorbs +1792*ph bytes.
//  - bases/coefs via R10's proven s_load path (tiny prep kernel).
//  - launch_bounds(1024,8): VGPR cap 64 = what R10/R12 naturally used.

#define B_  64
#define C_  32
#define H_  32
#define W_  32
#define K_  64
#define P_  784
#define CHW (C_*H_*W_)      // 32768 floats
#define HW  (H_*W_)         // 1024
#define SITES (K_*P_)       // 50176
#define NPAIRH 196          // pairs per p-half
#define NROWS 18            // staged image rows per half
#define SIMGF (C_*NROWS*W_) // 18432 floats = 72 KB

__constant__ float COEF_[16][4] = {
    {0, 0, 0, 0}, {0, 0, 0, 1}, {0, 1, 0, -1}, {0, 1, 0, 0},
    {0, 0, 1, -1}, {0, 0, 1, 0}, {0, 1, 1, -2}, {0, 1, 1, -1},
    {1, -1, -1, 1}, {1, -1, -1, 2}, {1, 0, -1, 0}, {1, 0, -1, 1},
    {1, -1, 0, 0}, {1, -1, 0, 1}, {1, 0, 0, -1}, {1, 0, 0, 0}
};

// ---- kernel 1: prep = bases (0..2047: baseG+baseL) + coefs (2048..4031) ----
__global__ __launch_bounds__(256) void prep_kernel(
    const int* __restrict__ a_idx, const int* __restrict__ b_idx,
    const float* __restrict__ w0, const float* __restrict__ w1,
    const float* __restrict__ w2, const float* __restrict__ w3,
    const float* __restrict__ w4,
    int* __restrict__ baseG,         // [K_][32] byte offsets, full image
    int* __restrict__ baseL,         // [K_][32] byte offsets, 18-row LDS tile
    float4* __restrict__ cws)        // [K_*31]
{
    const int t = blockIdx.x * 256 + threadIdx.x;
    if (t < K_ * 32) {
        const int k = t >> 5;
        const int j = t & 31;
        const int* src = (j < 16) ? a_idx : b_idx;
        const int l = j & 15;
        const size_t ii = ((size_t)k * P_ * 16 + l) * 3;   // site (k, p=0, l)
        const int h = src[ii + 0];   // = h_off  (hg=0 at p=0)
        const int w = src[ii + 1];   // = w_off
        const int c = src[ii + 2];
        baseG[t] = (c << 12) + (h << 7) + (w << 2);
        baseL[t] = (c * 2304) + (h << 7) + (w << 2);       // c*576*4
    } else if (t < K_ * 32 + K_ * 31) {
        const int tt = t - K_ * 32;
        const int k = tt / 31;
        const int node = tt - k * 31;
        int d, l;
        if      (node < 16) { d = 0; l = node; }
        else if (node < 24) { d = 1; l = node - 16; }
        else if (node < 28) { d = 2; l = node - 24; }
        else if (node < 30) { d = 3; l = node - 28; }
        else                { d = 4; l = 0; }
        const float* W;
        switch (d) {
            case 0: W = w0; break;
            case 1: W = w1; break;
            case 2: W = w2; break;
            case 3: W = w3; break;
            default: W = w4; break;
        }
        const float* row = W + ((size_t)l * K_ + k) * 16;
        float m = row[0];
        #pragma unroll
        for (int o = 1; o < 16; ++o) m = fmaxf(m, row[o]);
        float e[16];
        float Z = 0.0f;
        #pragma unroll
        for (int o = 0; o < 16; ++o) { e[o] = expf(row[o] - m); Z += e[o]; }
        const float inv = 1.0f / Z;
        float c0 = 0.f, c1 = 0.f, c2 = 0.f, c3 = 0.f;
        #pragma unroll
        for (int o = 0; o < 16; ++o) {
            c0 += e[o] * COEF_[o][0];
            c1 += e[o] * COEF_[o][1];
            c2 += e[o] * COEF_[o][2];
            c3 += e[o] * COEF_[o][3];
        }
        cws[tt] = make_float4(c0 * inv, c1 * inv, c2 * inv, c3 * inv);
    }
}

// y = c0 + c1*a + c2*b + c3*a*b == fma(b, fma(c3,a,c2), fma(c1,a,c0))
__device__ __forceinline__ float binop(float a, float b, float4 c) {
    return fmaf(b, fmaf(c.w, a, c.z), fmaf(c.y, a, c.x));
}

// ---- kernel 2: main. bid = ((kq*2+ph)<<5) | bp. 1024 thr, 2 blocks/CU. ----
__global__ __launch_bounds__(1024, 8) void logicconv_main(
    const float* __restrict__ x,
    const int* __restrict__ baseG,
    const int* __restrict__ baseL,
    const float4* __restrict__ cws,
    float* __restrict__ out)
{
    __shared__ float simg[SIMGF];   // 72 KB: even-image rows [14ph, 14ph+18)

    const int tid = threadIdx.x;
    const int bid = blockIdx.x;
    const int bp  = bid & 31;          // fastest -> XCD shares bp%8
    const int ph  = (bid >> 5) & 1;    // p-half
    const int kq  = bid >> 6;          // 0..3 (16 k's each)
    const int b0  = bp * 2;
    const int rlo = 14 * ph;

    // ---- stage even-image rows [rlo, rlo+18) of all 32 channels ----
    {
        const float4* xi = (const float4*)(x + (size_t)b0 * CHW + rlo * W_);
        float4* si = (float4*)simg;
        #pragma unroll
        for (int r = 0; r < 5; ++r) {
            const int u = r * 1024 + tid;           // float4 task, < 4608
            if (u < 4608) {
                const int c = u / 144;              // channel
                const int j = u - c * 144;          // float4 within tile row
                si[u] = xi[c * 256 + j];            // c*1024 elems = 256 f4
            }
        }
    }
    __syncthreads();

    // ---- 16 waves; wave g owns k = kq*16 + g ----
    const int g    = __builtin_amdgcn_readfirstlane(tid >> 6);
    const int lane = tid & 63;
    const int k    = kq * 16 + g;

    const int*    __restrict__ bG = baseG + k * 32;           // s_load
    const int*    __restrict__ bL = baseL + k * 32;           // s_load
    const float4* __restrict__ cw = cws + (size_t)k * 31;     // s_load
    const char*   sb = (const char*)simg;
    const char*   x1 = (const char*)(x + (size_t)(b0 + 1) * CHW) + 1792 * ph;
    float* __restrict__ o0 = out + ((size_t)b0 * K_ + k) * P_ + 392 * ph;
    float* __restrict__ o1 = o0 + (size_t)K_ * P_;

    for (int s = 0; s < 4; ++s) {
        const int t = s * 64 + lane;           // local pair index
        if (t < NPAIRH) {
            const unsigned row  = (unsigned)t / 14u;
            const unsigned disp = 8u * (unsigned)t + 16u * row;  // bytes

            float2 ye[16], yo[16];
            #pragma unroll
            for (int h = 0; h < 2; ++h) {
                // 1) odd-image global loads for this half (long latency first)
                float od[32];
                #pragma unroll
                for (int j = 0; j < 8; ++j) {
                    const int l = h * 8 + j;
                    const unsigned ga = (unsigned)bG[l]      + disp;
                    const unsigned gb = (unsigned)bG[16 + l] + disp;
                    od[4*j+0] = *(const float*)(x1 + ga);
                    od[4*j+1] = *(const float*)(x1 + ga + 4);
                    od[4*j+2] = *(const float*)(x1 + gb);
                    od[4*j+3] = *(const float*)(x1 + gb + 4);
                }
                // 2) even-image LDS pair reads (ds_read2_b32)
                float ev[32];
                #pragma unroll
                for (int j = 0; j < 8; ++j) {
                    const int l = h * 8 + j;
                    const unsigned la = (unsigned)bL[l]      + disp;
                    const unsigned lb = (unsigned)bL[16 + l] + disp;
                    ev[4*j+0] = *(const float*)(sb + la);
                    ev[4*j+1] = *(const float*)(sb + la + 4);
                    ev[4*j+2] = *(const float*)(sb + lb);
                    ev[4*j+3] = *(const float*)(sb + lb + 4);
                }
                // 3) layer-0 for this half
                #pragma unroll
                for (int j = 0; j < 8; ++j) {
                    const int l = h * 8 + j;
                    const float4 c = cw[l];
                    ye[l].x = binop(ev[4*j+0], ev[4*j+2], c);
                    ye[l].y = binop(ev[4*j+1], ev[4*j+3], c);
                    yo[l].x = binop(od[4*j+0], od[4*j+2], c);
                    yo[l].y = binop(od[4*j+1], od[4*j+3], c);
                }
            }
            #pragma unroll
            for (int l = 0; l < 8; ++l) {
                const float4 c = cw[16 + l];
                ye[l].x = binop(ye[2*l].x, ye[2*l+1].x, c);
                ye[l].y = binop(ye[2*l].y, ye[2*l+1].y, c);
                yo[l].x = binop(yo[2*l].x, yo[2*l+1].x, c);
                yo[l].y = binop(yo[2*l].y, yo[2*l+1].y, c);
            }
            #pragma unroll
            for (int l = 0; l < 4; ++l) {
                const float4 c = cw[24 + l];
                ye[l].x = binop(ye[2*l].x, ye[2*l+1].x, c);
                ye[l].y = binop(ye[2*l].y, ye[2*l+1].y, c);
                yo[l].x = binop(yo[2*l].x, yo[2*l+1].x, c);
                yo[l].y = binop(yo[2*l].y, yo[2*l+1].y, c);
            }
            #pragma unroll
            for (int l = 0; l < 2; ++l) {
                const float4 c = cw[28 + l];
                ye[l].x = binop(ye[2*l].x, ye[2*l+1].x, c);
                ye[l].y = binop(ye[2*l].y, ye[2*l+1].y, c);
                yo[l].x = binop(yo[2*l].x, yo[2*l+1].x, c);
                yo[l].y = binop(yo[2*l].y, yo[2*l+1].y, c);
            }
            {
                const float4 c = cw[30];
                float2 re, ro;
                re.x = binop(ye[0].x, ye[1].x, c);
                re.y = binop(ye[0].y, ye[1].y, c);
                ro.x = binop(yo[0].x, yo[1].x, c);
                ro.y = binop(yo[0].y, yo[1].y, c);
                *(float2*)(o0 + 2 * t) = re;
                *(float2*)(o1 + 2 * t) = ro;
            }
        }
    }
}

extern "C" void kernel_launch(void* const* d_in, const int* in_sizes, int n_in,
                              void* d_out, int out_size, void* d_ws, size_t ws_size,
                              hipStream_t stream) {
    const float* x     = (const float*)d_in[0];
    const float* w0    = (const float*)d_in[1];
    const float* w1    = (const float*)d_in[2];
    const float* w2    = (const float*)d_in[3];
    const float* w3    = (const float*)d_in[4];
    const float* w4    = (const float*)d_in[5];
    const int*   a_idx = (const int*)d_in[6];
    const int*   b_idx = (const int*)d_in[7];
    float* out = (float*)d_out;

    // ws layout: baseG (8 KB) | baseL (8 KB) | cws (32 KB)
    int*    baseG = (int*)d_ws;
    int*    baseL = baseG + K_ * 32;
    float4* cws   = (float4*)(baseL + K_ * 32);

    prep_kernel<<<16, 256, 0, stream>>>(a_idx, b_idx, w0, w1, w2, w3, w4,
                                        baseG, baseL, cws);

    logicconv_main<<<256, 1024, 0, stream>>>(x, baseG, baseL, cws, out);
}

// Round 16
// 33.357 us; speedup vs baseline: 1.3743x; 1.3743x over previous
//
#include <hip/hip_runtime.h>
#include <hip/hip_bf16.h>

// LogicConv3d: B=64, C=32, H=32, W=32, K=64, P=784, S=16 gathers/side.
// R16: R10 dual-pipe structure + depth-1 software pipeline on the odd-image
// global gathers.
//  - R13/R15: >4 waves/SIMD unreachable (needs ~100 live VGPR; caps spill).
//  - So hide L2 latency with ILP instead: per half-step (8 leaves), issue
//    the NEXT half-step's 16 global dwordx2 before computing the current
//    one (16 ds_read2 + layer0/1 ~ 400-500cyc covers ~300cyc L2 latency).
//    First half-step's loads issue BEFORE the staging barrier.
//  - Layer-1 folded eagerly per leaf-pair: y-state 64 -> 32 regs; ds reads
//    in quarters (4 leaves) to cap transient ev at 16 regs. Peak ~120 VGPR.
//  - Everything else = R10: 2-kernel (s_load bases/coefs), analytic offsets,
//    ds_read2 even-image gathers, kg-slow grid, float2 stores.

#define B_  64
#define C_  32
#define H_  32
#define W_  32
#define K_  64
#define P_  784
#define CHW (C_*H_*W_)      // 32768 floats = 128 KB
#define HW  (H_*W_)         // 1024
#define SITES (K_*P_)       // 50176
#define NPAIR (P_/2)        // 392

__constant__ float COEF_[16][4] = {
    {0, 0, 0, 0}, {0, 0, 0, 1}, {0, 1, 0, -1}, {0, 1, 0, 0},
    {0, 0, 1, -1}, {0, 0, 1, 0}, {0, 1, 1, -2}, {0, 1, 1, -1},
    {1, -1, -1, 1}, {1, -1, -1, 2}, {1, 0, -1, 0}, {1, 0, -1, 1},
    {1, -1, 0, 0}, {1, -1, 0, 1}, {1, 0, 0, -1}, {1, 0, 0, 0}
};

// ---- kernel 1: tiny prep = bases (0..2047) + coefs (2048..4031) ----
__global__ __launch_bounds__(256) void prep_kernel(
    const int* __restrict__ a_idx, const int* __restrict__ b_idx,
    const float* __restrict__ w0, const float* __restrict__ w1,
    const float* __restrict__ w2, const float* __restrict__ w3,
    const float* __restrict__ w4,
    int* __restrict__ baseAB,        // [K_][32] byte offsets
    float4* __restrict__ cws)        // [K_*31]
{
    const int t = blockIdx.x * 256 + threadIdx.x;
    if (t < K_ * 32) {
        const int k = t >> 5;
        const int j = t & 31;
        const int* src = (j < 16) ? a_idx : b_idx;
        const int l = j & 15;
        const size_t ii = ((size_t)k * P_ * 16 + l) * 3;   // site (k, p=0, l)
        const int h = src[ii + 0];
        const int w = src[ii + 1];
        const int c = src[ii + 2];
        baseAB[t] = (c << 12) + (h << 7) + (w << 2);       // bytes
    } else if (t < K_ * 32 + K_ * 31) {
        const int tt = t - K_ * 32;
        const int k = tt / 31;
        const int node = tt - k * 31;
        int d, l;
        if      (node < 16) { d = 0; l = node; }
        else if (node < 24) { d = 1; l = node - 16; }
        else if (node < 28) { d = 2; l = node - 24; }
        else if (node < 30) { d = 3; l = node - 28; }
        else                { d = 4; l = 0; }
        const float* W;
        switch (d) {
            case 0: W = w0; break;
            case 1: W = w1; break;
            case 2: W = w2; break;
            case 3: W = w3; break;
            default: W = w4; break;
        }
        const float* row = W + ((size_t)l * K_ + k) * 16;
        float m = row[0];
        #pragma unroll
        for (int o = 1; o < 16; ++o) m = fmaxf(m, row[o]);
        float e[16];
        float Z = 0.0f;
        #pragma unroll
        for (int o = 0; o < 16; ++o) { e[o] = expf(row[o] - m); Z += e[o]; }
        const float inv = 1.0f / Z;
        float c0 = 0.f, c1 = 0.f, c2 = 0.f, c3 = 0.f;
        #pragma unroll
        for (int o = 0; o < 16; ++o) {
            c0 += e[o] * COEF_[o][0];
            c1 += e[o] * COEF_[o][1];
            c2 += e[o] * COEF_[o][2];
            c3 += e[o] * COEF_[o][3];
        }
        cws[tt] = make_float4(c0 * inv, c1 * inv, c2 * inv, c3 * inv);
    }
}

// y = c0 + c1*a + c2*b + c3*a*b == fma(b, fma(c3,a,c2), fma(c1,a,c0))
__device__ __forceinline__ float binop(float a, float b, float4 c) {
    return fmaf(b, fmaf(c.w, a, c.z), fmaf(c.y, a, c.x));
}

// ---- kernel 2: main. bid = kg*32 + bp. 1024 thr, 1 block/CU. ----
__global__ __launch_bounds__(1024, 4) void logicconv_main(
    const float* __restrict__ x,
    const int* __restrict__ baseAB,
    const float4* __restrict__ cws,
    float* __restrict__ out)
{
    __shared__ float simg[CHW];   // even image, 128 KB

    const int tid = threadIdx.x;
    const int kg  = blockIdx.x >> 5;   // 0..7  (slow)
    const int bp  = blockIdx.x & 31;   // 0..31 (fast)
    const int b0  = bp * 2;

    const int g    = __builtin_amdgcn_readfirstlane(tid >> 7);
    const int lane = tid & 127;
    const int k    = kg * 8 + g;

    const int*    __restrict__ bA = baseAB + k * 32;          // s_load
    const float4* __restrict__ cw = cws + (size_t)k * 31;     // s_load
    const char*   sb = (const char*)simg;
    const char*   x1 = (const char*)(x + (size_t)(b0 + 1) * CHW);  // odd image
    float* __restrict__ o0 = out + ((size_t)b0 * K_ + k) * P_;
    float* __restrict__ o1 = o0 + (size_t)K_ * P_;

    // per-s byte displacement (clamped so all lanes compute in-bounds addrs)
    unsigned disp[4];
    #pragma unroll
    for (int s = 0; s < 4; ++s) {
        unsigned t = s * 128 + lane;
        if (t > NPAIR - 1) t = NPAIR - 1;
        disp[s] = 8u * t + 16u * (t / 14u);
    }

    float odA[32], odB[32];
    float2 y1e[8], y1o[8];

    // issue 16 global dwordx2 for (s,h): 8 leaves x 2 sides x 2 elems
    #define ODLOAD(dst, hh, ss)                                        \
        _Pragma("unroll")                                              \
        for (int j = 0; j < 8; ++j) {                                  \
            const int l = (hh) * 8 + j;                                \
            const unsigned ga = (unsigned)bA[l]      + disp[ss];       \
            const unsigned gb = (unsigned)bA[16 + l] + disp[ss];       \
            dst[4*j+0] = *(const float*)(x1 + ga);                     \
            dst[4*j+1] = *(const float*)(x1 + ga + 4);                 \
            dst[4*j+2] = *(const float*)(x1 + gb);                     \
            dst[4*j+3] = *(const float*)(x1 + gb + 4);                 \
        }

    // ds reads (quarters of 4 leaves) + layer0 + eager layer1 for half hh
    #define EVL0L1(od, hh, ss)                                             \
        _Pragma("unroll")                                                  \
        for (int q = 0; q < 2; ++q) {                                      \
            float ev[16];                                                  \
            _Pragma("unroll")                                              \
            for (int j = 0; j < 4; ++j) {                                  \
                const int l = (hh) * 8 + q * 4 + j;                        \
                const unsigned la = (unsigned)bA[l]      + disp[ss];       \
                const unsigned lb = (unsigned)bA[16 + l] + disp[ss];       \
                ev[4*j+0] = *(const float*)(sb + la);                      \
                ev[4*j+1] = *(const float*)(sb + la + 4);                  \
                ev[4*j+2] = *(const float*)(sb + lb);                      \
                ev[4*j+3] = *(const float*)(sb + lb + 4);                  \
            }                                                              \
            _Pragma("unroll")                                              \
            for (int j = 0; j < 2; ++j) {                                  \
                const int l0 = (hh) * 8 + q * 4 + 2 * j;                   \
                const int n1 = (hh) * 4 + q * 2 + j;   /* layer1 node */   \
                const float4 c0 = cw[l0], c1 = cw[l0 + 1];                 \
                const float4 cL = cw[16 + n1];                             \
                const int e0i = 8 * j, o0i = 16 * q + 8 * j;               \
                float e0x = binop(ev[e0i+0], ev[e0i+2], c0);               \
                float e0y = binop(ev[e0i+1], ev[e0i+3], c0);               \
                float e1x = binop(ev[e0i+4], ev[e0i+6], c1);               \
                float e1y = binop(ev[e0i+5], ev[e0i+7], c1);               \
                float q0x = binop(od[o0i+0], od[o0i+2], c0);               \
                float q0y = binop(od[o0i+1], od[o0i+3], c0);               \
                float q1x = binop(od[o0i+4], od[o0i+6], c1);               \
                float q1y = binop(od[o0i+5], od[o0i+7], c1);               \
                y1e[n1].x = binop(e0x, e1x, cL);                           \
                y1e[n1].y = binop(e0y, e1y, cL);                           \
                y1o[n1].x = binop(q0x, q1x, cL);                           \
                y1o[n1].y = binop(q0y, q1y, cL);                           \
            }                                                              \
        }

    #define FINISH(ss)                                                     \
        {                                                                  \
            float2 y2e[4], y2o[4];                                         \
            _Pragma("unroll")                                              \
            for (int l = 0; l < 4; ++l) {                                  \
                const float4 c = cw[24 + l];                               \
                y2e[l].x = binop(y1e[2*l].x, y1e[2*l+1].x, c);             \
                y2e[l].y = binop(y1e[2*l].y, y1e[2*l+1].y, c);             \
                y2o[l].x = binop(y1o[2*l].x, y1o[2*l+1].x, c);             \
                y2o[l].y = binop(y1o[2*l].y, y1o[2*l+1].y, c);             \
            }                                                              \
            float2 y3e[2], y3o[2];                                         \
            _Pragma("unroll")                                              \
            for (int l = 0; l < 2; ++l) {                                  \
                const float4 c = cw[28 + l];                               \
                y3e[l].x = binop(y2e[2*l].x, y2e[2*l+1].x, c);             \
                y3e[l].y = binop(y2e[2*l].y, y2e[2*l+1].y, c);             \
                y3o[l].x = binop(y2o[2*l].x, y2o[2*l+1].x, c);             \
                y3o[l].y = binop(y2o[2*l].y, y2o[2*l+1].y, c);             \
            }                                                              \
            const float4 c4 = cw[30];                                      \
            float2 re, ro;                                                 \
            re.x = binop(y3e[0].x, y3e[1].x, c4);                          \
            re.y = binop(y3e[0].y, y3e[1].y, c4);                          \
            ro.x = binop(y3o[0].x, y3o[1].x, c4);                          \
            ro.y = binop(y3o[0].y, y3o[1].y, c4);                          \
            const int tt = (ss) * 128 + lane;                              \
            if (tt < NPAIR) {                                              \
                *(float2*)(o0 + 2 * tt) = re;                              \
                *(float2*)(o1 + 2 * tt) = ro;                              \
            }                                                              \
        }

    // ---- prologue: issue first half-step's globals, then stage ----
    ODLOAD(odA, 0, 0)
    {
        const float4* xi = (const float4*)(x + (size_t)b0 * CHW);
        float4* si = (float4*)simg;
        #pragma unroll
        for (int j = 0; j < 8; ++j)
            si[tid + j * 1024] = xi[tid + j * 1024];
    }
    __syncthreads();

    // ---- pipelined half-steps: load (i+1) || compute (i) ----
    ODLOAD(odB, 1, 0)  EVL0L1(odA, 0, 0)
    ODLOAD(odA, 0, 1)  EVL0L1(odB, 1, 0)  FINISH(0)
    ODLOAD(odB, 1, 1)  EVL0L1(odA, 0, 1)
    ODLOAD(odA, 0, 2)  EVL0L1(odB, 1, 1)  FINISH(1)
    ODLOAD(odB, 1, 2)  EVL0L1(odA, 0, 2)
    ODLOAD(odA, 0, 3)  EVL0L1(odB, 1, 2)  FINISH(2)
    ODLOAD(odB, 1, 3)  EVL0L1(odA, 0, 3)
                       EVL0L1(odB, 1, 3)  FINISH(3)

    #undef ODLOAD
    #undef EVL0L1
    #undef FINISH
}

extern "C" void kernel_launch(void* const* d_in, const int* in_sizes, int n_in,
                              void* d_out, int out_size, void* d_ws, size_t ws_size,
                              hipStream_t stream) {
    const float* x     = (const float*)d_in[0];
    const float* w0    = (const float*)d_in[1];
    const float* w1    = (const float*)d_in[2];
    const float* w2    = (const float*)d_in[3];
    const float* w3    = (const float*)d_in[4];
    const float* w4    = (const float*)d_in[5];
    const int*   a_idx = (const int*)d_in[6];
    const int*   b_idx = (const int*)d_in[7];
    float* out = (float*)d_out;

    // ws layout: baseAB (8 KB) | cws (32 KB)
    int*    baseAB = (int*)d_ws;
    float4* cws    = (float4*)((char*)d_ws + (size_t)K_ * 32 * 4);

    prep_kernel<<<16, 256, 0, stream>>>(a_idx, b_idx, w0, w1, w2, w3, w4,
                                        baseAB, cws);

    logicconv_main<<<256, 1024, 0, stream>>>(x, baseAB, cws, out);
}